// Round 2
// baseline (98.451 us; speedup 1.0000x reference)
//
#include <hip/hip_runtime.h>
#include <hip/hip_cooperative_groups.h>

namespace cg = cooperative_groups;

// Problem constants (fixed by setup_inputs): N=65536 tokens, K=8, E=64 experts.
#define TOTAL   524288            // N*K flattened assignments
#define NEXP    64
#define TOPK    8
#define GSIZE   256               // blocks (1 per CU) -- all co-resident (cooperative)
#define BLOCK   1024              // threads = 16 waves -> 4 waves/SIMD
#define NWAVE   16
#define CHUNK   (TOTAL / GSIZE)   // 2048 elements per block (2 per thread)
#define ROWSPW  (GSIZE / NWAVE)   // 16 count-rows scanned per wave

// Mask of lanes whose ballot-encoded expert equals x (x in [0,64)).
// bb[bit] = __ballot of bit 'bit' of each lane's expert id (wave-uniform).
__device__ __forceinline__ unsigned long long expert_mask(
        const unsigned long long bb[6], int x) {
    unsigned long long m = ~0ULL;
#pragma unroll
    for (int bit = 0; bit < 6; bit++)
        m &= ((x >> bit) & 1) ? bb[bit] : ~bb[bit];
    return m;
}

// One fused cooperative kernel: histogram -> grid barrier -> scan -> scatter.
// Element data (expert ids, scores, same-expert masks) stays register-resident
// across the grid sync; only the 64-int per-block counts row goes through L2.
__global__ __launch_bounds__(BLOCK) void fused_kernel(
        const float* __restrict__ scores,
        const int*   __restrict__ idx,
        int*         __restrict__ counts,
        float*       __restrict__ out_scores,
        float*       __restrict__ out_tok,
        float*       __restrict__ out_cnt) {
    __shared__ int wtot[NWAVE][NEXP];       // this block: per-wave expert counts
    __shared__ int part_pre[NWAVE][NEXP];   // per-wave partial: counts in blocks < b
    __shared__ int part_tot[NWAVE][NEXP];   // per-wave partial: global totals
    __shared__ int exscan_pre[NEXP];        // expert ex-scan + this block's prefix

    const int tid = threadIdx.x, lane = tid & 63, wave = tid >> 6, b = blockIdx.x;
    const unsigned long long lt  = (1ULL << lane) - 1ULL;
    const unsigned long long own = 1ULL << lane;

    // --- element loads (coalesced 8B each) ---
    const int2   e2 = ((const int2*)idx)[b * (CHUNK / 2) + tid];
    const float2 s2 = ((const float2*)scores)[b * (CHUNK / 2) + tid];

    // --- ballots + lane-as-expert masks (registers only) ---
    const int e0 = e2.x, e1 = e2.y;
    unsigned long long bb0[6], bb1[6];
#pragma unroll
    for (int bit = 0; bit < 6; bit++) {
        bb0[bit] = __ballot((e0 >> bit) & 1);
        bb1[bit] = __ballot((e1 >> bit) & 1);
    }
    const unsigned long long M0 = expert_mask(bb0, lane);  // lanes with slot-0 expert == lane
    const unsigned long long M1 = expert_mask(bb1, lane);  // lanes with slot-1 expert == lane
    wtot[wave][lane] = __popcll(M0) + __popcll(M1);
    __syncthreads();

    // --- publish this block's 64-expert counts row ---
    if (wave == 0) {
        int t = 0;
#pragma unroll
        for (int w = 0; w < NWAVE; w++) t += wtot[w][lane];
        counts[b * NEXP + lane] = t;
    }

    // --- grid-wide barrier: all counts rows visible after this ---
    cg::this_grid().sync();

    // --- counts scan: expert = lane, 16 rows per wave (independent L2 loads) ---
    int pre = 0, tot = 0;
    {
        const int r0 = wave * ROWSPW;
#pragma unroll
        for (int q = 0; q < ROWSPW; q++) {
            const int bb = r0 + q;
            const int c  = counts[bb * NEXP + lane];   // lane-coalesced row
            tot += c;
            pre += (bb < b) ? c : 0;
        }
    }
    part_pre[wave][lane] = pre;
    part_tot[wave][lane] = tot;
    __syncthreads();

    // --- combine partials + expert exclusive scan (wave 0, shfl-based) ---
    if (wave == 0) {
        int p = 0, t = 0;
#pragma unroll
        for (int w = 0; w < NWAVE; w++) {
            p += part_pre[w][lane];
            t += part_tot[w][lane];
        }
        if (b == 0) out_cnt[lane] = (float)t;   // num_tokens_per_expert (fp32)
        int inc = t;                            // 64-lane inclusive scan
#pragma unroll
        for (int d = 1; d < 64; d <<= 1) {
            const int v = __shfl_up(inc, d, 64);
            if (lane >= d) inc += v;
        }
        exscan_pre[lane] = (inc - t) + p;       // exclusive scan + block prefix
    }
    __syncthreads();

    // --- per-lane (= per-expert) wave start offset, register-resident ---
    int base = exscan_pre[lane];
#pragma unroll
    for (int w = 0; w < NWAVE; w++)
        base += (w < wave) ? wtot[w][lane] : 0;

    // --- fetch cross-expert masks/offsets from the owning lane ---
    const unsigned long long own0 = __shfl(M0, e0, 64);   // M0(e0)
    const unsigned long long own1 = __shfl(M1, e1, 64);   // M1(e1)
    const unsigned long long c01  = __shfl(M1, e0, 64);   // M1(e0)
    const unsigned long long c10  = __shfl(M0, e1, 64);   // M0(e1)
    const int base0 = __shfl(base, e0, 64);
    const int base1 = __shfl(base, e1, 64);

    // stable in-wave ranks (flat order = 2*lane + sub)
    const int rank0 = __popcll(own0 & lt) + __popcll(c01 & lt);
    const int rank1 = __popcll(c10 & (lt | own)) + __popcll(own1 & lt);

    const int f0   = b * CHUNK + 2 * tid;      // flattened assignment index (sub 0)
    const int pos0 = base0 + rank0;
    const int pos1 = base1 + rank1;

    out_scores[pos0] = s2.x;
    out_scores[pos1] = s2.y;
    out_tok[pos0]    = (float)(f0 >> 3);        // /TOPK, exact in fp32 (<65536)
    out_tok[pos1]    = (float)((f0 + 1) >> 3);
}

extern "C" void kernel_launch(void* const* d_in, const int* in_sizes, int n_in,
                              void* d_out, int out_size, void* d_ws, size_t ws_size,
                              hipStream_t stream) {
    const float* top_scores = (const float*)d_in[0];
    const int*   sel_idx    = (const int*)d_in[1];
    float*       out        = (float*)d_out;
    int*         counts     = (int*)d_ws;   // GSIZE*NEXP ints = 64 KB

    // d_out layout: [scores_sorted (TOTAL)] [token_idx_sorted (TOTAL)] [counts (NEXP)]
    float* out_scores = out;
    float* out_tok    = out + TOTAL;
    float* out_cnt    = out + 2 * TOTAL;

    void* args[] = {(void*)&top_scores, (void*)&sel_idx, (void*)&counts,
                    (void*)&out_scores, (void*)&out_tok, (void*)&out_cnt};
    hipLaunchCooperativeKernel((void*)fused_kernel, dim3(GSIZE), dim3(BLOCK),
                               args, 0, stream);
}

// Round 3
// 66.632 us; speedup vs baseline: 1.4775x; 1.4775x over previous
//
#include <hip/hip_runtime.h>

// Problem constants (fixed by setup_inputs): N=65536 tokens, K=8, E=64 experts.
#define TOTAL   524288            // N*K flattened assignments
#define NEXP    64
#define TOPK    8
#define GSIZE   256               // blocks (1 per CU)
#define BLOCK   1024              // threads = 16 waves -> 4 waves/SIMD
#define NWAVE   16
#define CHUNK   (TOTAL / GSIZE)   // 2048 elements per block (2 per thread)
#define ROWSPW  (GSIZE / NWAVE)   // 16 count-rows scanned per wave

// Mask of lanes whose ballot-encoded expert equals x (x in [0,64)).
__device__ __forceinline__ unsigned long long expert_mask(
        const unsigned long long bb[6], int x) {
    unsigned long long m = ~0ULL;
#pragma unroll
    for (int bit = 0; bit < 6; bit++)
        m &= ((x >> bit) & 1) ? bb[bit] : ~bb[bit];
    return m;
}

// ---------------- Kernel A: per-block expert histogram ----------------------
__global__ __launch_bounds__(BLOCK) void hist_kernel(const int* __restrict__ idx,
                                                     int* __restrict__ counts) {
    __shared__ int hist[NWAVE][NEXP];
    const int tid = threadIdx.x, lane = tid & 63, wave = tid >> 6;

    const int2 e2 = ((const int2*)idx)[blockIdx.x * (CHUNK / 2) + tid];  // coalesced 8B

    unsigned long long bb0[6], bb1[6];
#pragma unroll
    for (int bit = 0; bit < 6; bit++) {
        bb0[bit] = __ballot((e2.x >> bit) & 1);
        bb1[bit] = __ballot((e2.y >> bit) & 1);
    }
    hist[wave][lane] = __popcll(expert_mask(bb0, lane)) +
                       __popcll(expert_mask(bb1, lane));
    __syncthreads();
    if (tid < NEXP) {
        int s = 0;
#pragma unroll
        for (int w = 0; w < NWAVE; w++) s += hist[w][tid];
        counts[blockIdx.x * NEXP + tid] = s;
    }
}

// ---------------- Kernel B: offsets + LDS-staged coalesced scatter ----------
__global__ __launch_bounds__(BLOCK) void scatter_kernel(
        const float* __restrict__ scores,
        const int*   __restrict__ idx,
        const int*   __restrict__ counts,
        float*       __restrict__ out_scores,
        float*       __restrict__ out_tok,
        float*       __restrict__ out_cnt) {
    __shared__ int   wtot[NWAVE][NEXP];     // this block: per-wave expert counts
    __shared__ int   part_pre[NWAVE][NEXP]; // per-wave partial: counts in blocks < b
    __shared__ int   part_tot[NWAVE][NEXP]; // per-wave partial: global totals
    __shared__ int   exscan_pre[NEXP];      // expert ex-scan + this block's prefix
    __shared__ float sc_s[CHUNK];           // block-sorted scores
    __shared__ float tk_s[CHUNK];           // block-sorted token indices (fp32)
    __shared__ int   gp_s[CHUNK];           // global position per sorted slot

    const int tid = threadIdx.x, lane = tid & 63, wave = tid >> 6, b = blockIdx.x;
    const unsigned long long lt  = (1ULL << lane) - 1ULL;
    const unsigned long long own = 1ULL << lane;

    // --- element loads (coalesced 8B each) ---
    const int2   e2 = ((const int2*)idx)[b * (CHUNK / 2) + tid];
    const float2 s2 = ((const float2*)scores)[b * (CHUNK / 2) + tid];

    // --- counts scan: expert = lane, 16 rows per wave (independent L2 loads) ---
    int pre = 0, tot = 0;
    {
        const int r0 = wave * ROWSPW;
#pragma unroll
        for (int q = 0; q < ROWSPW; q++) {
            const int bb = r0 + q;
            const int c  = counts[bb * NEXP + lane];   // lane-coalesced row
            tot += c;
            pre += (bb < b) ? c : 0;
        }
    }
    part_pre[wave][lane] = pre;
    part_tot[wave][lane] = tot;

    // --- ballots + lane-as-expert masks (registers only) ---
    const int e0 = e2.x, e1 = e2.y;
    unsigned long long bb0[6], bb1[6];
#pragma unroll
    for (int bit = 0; bit < 6; bit++) {
        bb0[bit] = __ballot((e0 >> bit) & 1);
        bb1[bit] = __ballot((e1 >> bit) & 1);
    }
    const unsigned long long M0 = expert_mask(bb0, lane);
    const unsigned long long M1 = expert_mask(bb1, lane);
    wtot[wave][lane] = __popcll(M0) + __popcll(M1);
    __syncthreads();

    // --- every wave: block-local totals, prefix-by-wave, local expert scan ---
    int t_pre_w = 0, t_blk = 0;
#pragma unroll
    for (int w = 0; w < NWAVE; w++) {
        const int c = wtot[w][lane];
        t_pre_w += (w < wave) ? c : 0;
        t_blk   += c;
    }
    int linc = t_blk;                       // 64-lane inclusive scan (per wave, redundant)
#pragma unroll
    for (int d = 1; d < 64; d <<= 1) {
        const int v = __shfl_up(linc, d, 64);
        if (lane >= d) linc += v;
    }
    const int base_local = (linc - t_blk) + t_pre_w;   // this wave's local start for expert 'lane'

    // --- wave 0: combine partials + global expert exclusive scan ---
    if (wave == 0) {
        int p = 0, t = 0;
#pragma unroll
        for (int w = 0; w < NWAVE; w++) {
            p += part_pre[w][lane];
            t += part_tot[w][lane];
        }
        if (b == 0) out_cnt[lane] = (float)t;   // num_tokens_per_expert (fp32)
        int inc = t;
#pragma unroll
        for (int d = 1; d < 64; d <<= 1) {
            const int v = __shfl_up(inc, d, 64);
            if (lane >= d) inc += v;
        }
        exscan_pre[lane] = (inc - t) + p;       // exclusive scan + block prefix
    }
    __syncthreads();

    const int base_glob = exscan_pre[lane] + t_pre_w;  // this wave's global start for expert 'lane'

    // --- fetch cross-expert masks/offsets from the owning lane ---
    const unsigned long long own0 = __shfl(M0, e0, 64);
    const unsigned long long own1 = __shfl(M1, e1, 64);
    const unsigned long long c01  = __shfl(M1, e0, 64);
    const unsigned long long c10  = __shfl(M0, e1, 64);
    const int bl0 = __shfl(base_local, e0, 64);
    const int bl1 = __shfl(base_local, e1, 64);
    const int bg0 = __shfl(base_glob, e0, 64);
    const int bg1 = __shfl(base_glob, e1, 64);

    // stable in-wave ranks (flat order = 2*lane + sub)
    const int rank0 = __popcll(own0 & lt) + __popcll(c01 & lt);
    const int rank1 = __popcll(c10 & (lt | own)) + __popcll(own1 & lt);

    const int f0 = b * CHUNK + 2 * tid;         // flattened assignment index (sub 0)
    const int l0 = bl0 + rank0, l1 = bl1 + rank1;   // block-local sorted slots
    const int g0 = bg0 + rank0, g1 = bg1 + rank1;   // global sorted positions

    // --- stage into LDS in block-sorted order ---
    sc_s[l0] = s2.x;             sc_s[l1] = s2.y;
    tk_s[l0] = (float)(f0 >> 3); tk_s[l1] = (float)((f0 + 1) >> 3);
    gp_s[l0] = g0;               gp_s[l1] = g1;
    __syncthreads();

    // --- coalesced epilogue: consecutive slots -> consecutive global addrs ---
#pragma unroll
    for (int r = 0; r < 2; r++) {
        const int i = tid + r * BLOCK;
        const int p = gp_s[i];
        out_scores[p] = sc_s[i];
        out_tok[p]    = tk_s[i];
    }
}

extern "C" void kernel_launch(void* const* d_in, const int* in_sizes, int n_in,
                              void* d_out, int out_size, void* d_ws, size_t ws_size,
                              hipStream_t stream) {
    const float* top_scores = (const float*)d_in[0];
    const int*   sel_idx    = (const int*)d_in[1];
    float*       out        = (float*)d_out;
    int*         counts     = (int*)d_ws;   // GSIZE*NEXP ints = 64 KB

    // d_out layout: [scores_sorted (TOTAL)] [token_idx_sorted (TOTAL)] [counts (NEXP)]
    float* out_scores = out;
    float* out_tok    = out + TOTAL;
    float* out_cnt    = out + 2 * TOTAL;

    hist_kernel<<<GSIZE, BLOCK, 0, stream>>>(sel_idx, counts);
    scatter_kernel<<<GSIZE, BLOCK, 0, stream>>>(top_scores, sel_idx, counts,
                                                out_scores, out_tok, out_cnt);
}